// Round 10
// baseline (240.818 us; speedup 1.0000x reference)
//
#include <hip/hip_runtime.h>

// CentroidPool: N=65536 x K=4096 x D=128 fp32 -> argmin_k ||x - c_k|| (int32).
// Stage 1: f16x3-split MFMA GEMM (xh*ch + xh*cl + xl*ch, fp32 acc = c2 init),
//   top-2 via sortable packed keys, register ping-pong B pipeline, B pre-packed
//   in per-(tile,step,lane) fragment order -> every B load 64x16B coalesced.
// ROUND-23: r22's fused-rescore epilogue cost 11us (64 serial threads, 96
//   dependent 16B loads each, fp64 chain; 3/4 of block idle). Now 4 threads
//   per point (sub=t&3 -> 32 dims each) + __shfl_xor fp64 reduce -> ~4x less
//   exposed latency. split_pack_c2 vectorized: float4/thread, f16x4 stores,
//   32-lane shuffle c2 (no LDS/syncthreads), 512 blocks instead of 2048.
//   Loop body byte-identical to r18/r22 (167.7us standalone).
// Output written directly by argmin blocks.

typedef _Float16 f16;
typedef f16  f16x4 __attribute__((ext_vector_type(4)));
typedef f16  f16x8 __attribute__((ext_vector_type(8)));
typedef float f32x4 __attribute__((ext_vector_type(4)));

constexpr int N_PTS  = 65536;
constexpr int K_CENT = 4096;
constexpr int D_DIM  = 128;
constexpr int MB     = 64;     // points per block (4 waves share them)
constexpr int KW     = 1024;   // centroids per wave (waves split K 4-ways)
constexpr float SOFF = 256.0f; // score offset => strictly positive scores

// ---------------------------------------------------------------------------
// Split coords to f16 h/l, pack into fragment order, compute c2+SOFF.
// Vectorized: one float4 (4 dims of one cent) per thread.
// dst = ((gt*4 + ds)*2 + n)*512 + lane*8 + j, j0 = d0&7 in {0,4} -> f16x4.
// c2: 32 threads per cent, pure shuffle reduce (masks 1..16 stay in-group).
// ---------------------------------------------------------------------------
__global__ __launch_bounds__(256) void split_pack_c2(const float* __restrict__ c,
                                                     f16* __restrict__ chp,
                                                     f16* __restrict__ clp,
                                                     float* __restrict__ c2b) {
    const int t = threadIdx.x;
    const int idx = blockIdx.x * 256 + t;      // float4 index over K*D/4
    const int cent = idx >> 5;                 // 32 float4 per cent
    const int d0 = (idx & 31) * 4;             // starting dim
    float4 v = *(const float4*)(c + (size_t)cent * D_DIM + d0);
    f16 h0 = (f16)v.x, h1 = (f16)v.y, h2 = (f16)v.z, h3 = (f16)v.w;
    f16 l0 = (f16)(v.x - (float)h0), l1 = (f16)(v.y - (float)h1);
    f16 l2 = (f16)(v.z - (float)h2), l3 = (f16)(v.w - (float)h3);
    int gt = cent >> 5, n = (cent >> 4) & 1, l15c = cent & 15;
    int ds = d0 >> 5, quad = (d0 >> 3) & 3, j0 = d0 & 7;
    int lane = quad * 16 + l15c;
    int dst = ((gt * 4 + ds) * 2 + n) * 512 + lane * 8 + j0;
    *(f16x4*)(chp + dst) = (f16x4){h0, h1, h2, h3};
    *(f16x4*)(clp + dst) = (f16x4){l0, l1, l2, l3};
    // c2 reduction across the cent's 32 threads.
    float s = v.x * v.x + v.y * v.y + v.z * v.z + v.w * v.w;
#pragma unroll
    for (int m = 1; m < 32; m <<= 1) s += __shfl_xor(s, m, 64);
    if ((t & 31) == 0) c2b[cent] = s + SOFF;
}

// ---------------------------------------------------------------------------
// Stage 1 + fused rescore. Block = 4 waves x 64 points; latent (-2x) split h/l
// in XOR-swizzled LDS. Wave w scans cents [w*1024,(w+1)*1024) in 32-wide
// k-tiles (2 n-groups). Ping-pong invariant: Ba = (kt, ds0), offB -> (kt,ds1).
// key = (bits(score)&~63)|kn, kn = kt*2+n (6b); cent = (wave*64+kn)*16 + l15.
// Epilogue: t<64 merges block top-2 -> LDS; then ALL 256 threads rescore in
// fp64, 4 threads per point (32 dims each) + shfl_xor reduce.
// ---------------------------------------------------------------------------
__global__ __launch_bounds__(256, 2) void argmin_mfma(
        const float* __restrict__ latent,
        const float* __restrict__ coords,
        const f16*   __restrict__ chp,    // packed B hi
        const f16*   __restrict__ clp,    // packed B lo
        const float* __restrict__ c2b,
        int* __restrict__ out) {
    __shared__ f16 latH[MB * 128];
    __shared__ f16 latL[MB * 128];
    __shared__ unsigned r1K[4][MB]; __shared__ int r1I[4][MB];
    __shared__ unsigned r2K[4][MB]; __shared__ int r2I[4][MB];

    const int t    = threadIdx.x;
    const int wave = t >> 6;
    const int lane = t & 63;
    const int quad = lane >> 4;
    const int l15  = lane & 15;
    const int row0 = blockIdx.x * MB;

    {   // Stage latent: scale -2, split h/l, XOR-swizzle 16-B units.
        const float4* src = (const float4*)(latent + (size_t)row0 * D_DIM);
#pragma unroll
        for (int i = 0; i < 4; ++i) {
            int g  = i * 256 + t;          // float8 index in [0,1024)
            int r  = g >> 4;               // row (16 float8 per row)
            int c8 = g & 15;               // logical 16-B column
            float4 v0 = src[2 * g];
            float4 v1 = src[2 * g + 1];
            float xs[8] = {v0.x, v0.y, v0.z, v0.w, v1.x, v1.y, v1.z, v1.w};
            f16x8 hv, lv;
#pragma unroll
            for (int c = 0; c < 8; ++c) {
                float x = -2.0f * xs[c];
                f16 h = (f16)x;
                hv[c] = h;
                lv[c] = (f16)(x - (float)h);
            }
            int pc = ((c8 ^ (r & 15)) << 3);
            *(f16x8*)&latH[r * 128 + pc] = hv;
            *(f16x8*)&latL[r * 128 + pc] = lv;
        }
    }
    __syncthreads();

    unsigned b1[16], b2[16];
#pragma unroll
    for (int i = 0; i < 16; ++i) { b1[i] = 0xFFFFFFFFu; b2[i] = 0xFFFFFFFFu; }

    const int wbase = wave * KW;
    // Packed-B element offset of the next step's load: uniform +1024/step.
    unsigned offB = (unsigned)(wave * 32 * 4) * 1024u + (unsigned)(lane * 8);

    // Named ping-pong regs — never address-taken.
    f16x8 Ba0, Ba1, Ba2, Ba3, Bb0, Bb1, Bb2, Bb3;
    f32x4 a00, a01, a10, a11, a20, a21, a30, a31;

#define PFB(P) \
    P##0 = *(const f16x8*)(chp + offB); \
    P##1 = *(const f16x8*)(clp + offB); \
    P##2 = *(const f16x8*)(chp + offB + 512); \
    P##3 = *(const f16x8*)(clp + offB + 512);

#define MF(d, a, b) d = __builtin_amdgcn_mfma_f32_16x16x32_f16(a, b, d, 0, 0, 0);
#define MFC(d, a, b, c) d = __builtin_amdgcn_mfma_f32_16x16x32_f16(a, b, c, 0, 0, 0);

// ds>=1 step: accumulate into live accs. Prio 1 across the MFMA cluster.
#define STEP(P, ds) { \
    __builtin_amdgcn_s_setprio(1); \
    const int pc_ = ((((ds) << 2) + quad) ^ l15) << 3; \
    f16x8 ah_, al_; \
    ah_ = *(const f16x8*)&latH[(     l15) * 128 + pc_]; \
    al_ = *(const f16x8*)&latL[(     l15) * 128 + pc_]; \
    MF(a00, ah_, P##0) MF(a00, ah_, P##1) MF(a00, al_, P##0) \
    MF(a01, ah_, P##2) MF(a01, ah_, P##3) MF(a01, al_, P##2) \
    ah_ = *(const f16x8*)&latH[(16 + l15) * 128 + pc_]; \
    al_ = *(const f16x8*)&latL[(16 + l15) * 128 + pc_]; \
    MF(a10, ah_, P##0) MF(a10, ah_, P##1) MF(a10, al_, P##0) \
    MF(a11, ah_, P##2) MF(a11, ah_, P##3) MF(a11, al_, P##2) \
    ah_ = *(const f16x8*)&latH[(32 + l15) * 128 + pc_]; \
    al_ = *(const f16x8*)&latL[(32 + l15) * 128 + pc_]; \
    MF(a20, ah_, P##0) MF(a20, ah_, P##1) MF(a20, al_, P##0) \
    MF(a21, ah_, P##2) MF(a21, ah_, P##3) MF(a21, al_, P##2) \
    ah_ = *(const f16x8*)&latH[(48 + l15) * 128 + pc_]; \
    al_ = *(const f16x8*)&latL[(48 + l15) * 128 + pc_]; \
    MF(a30, ah_, P##0) MF(a30, ah_, P##1) MF(a30, al_, P##0) \
    MF(a31, ah_, P##2) MF(a31, ah_, P##3) MF(a31, al_, P##2) \
    __builtin_amdgcn_s_setprio(0); }

// ds==0 step: each acc's FIRST MFMA takes the c2 broadcast as C (no INIT pass).
#define STEP0(P) { \
    __builtin_amdgcn_s_setprio(1); \
    const int pc_ = (quad ^ l15) << 3; \
    f16x8 ah_, al_; \
    ah_ = *(const f16x8*)&latH[(     l15) * 128 + pc_]; \
    al_ = *(const f16x8*)&latL[(     l15) * 128 + pc_]; \
    MFC(a00, ah_, P##0, cvec0) MF(a00, ah_, P##1) MF(a00, al_, P##0) \
    MFC(a01, ah_, P##2, cvec1) MF(a01, ah_, P##3) MF(a01, al_, P##2) \
    ah_ = *(const f16x8*)&latH[(16 + l15) * 128 + pc_]; \
    al_ = *(const f16x8*)&latL[(16 + l15) * 128 + pc_]; \
    MFC(a10, ah_, P##0, cvec0) MF(a10, ah_, P##1) MF(a10, al_, P##0) \
    MFC(a11, ah_, P##2, cvec1) MF(a11, ah_, P##3) MF(a11, al_, P##2) \
    ah_ = *(const f16x8*)&latH[(32 + l15) * 128 + pc_]; \
    al_ = *(const f16x8*)&latL[(32 + l15) * 128 + pc_]; \
    MFC(a20, ah_, P##0, cvec0) MF(a20, ah_, P##1) MF(a20, al_, P##0) \
    MFC(a21, ah_, P##2, cvec1) MF(a21, ah_, P##3) MF(a21, al_, P##2) \
    ah_ = *(const f16x8*)&latH[(48 + l15) * 128 + pc_]; \
    al_ = *(const f16x8*)&latL[(48 + l15) * 128 + pc_]; \
    MFC(a30, ah_, P##0, cvec0) MF(a30, ah_, P##1) MF(a30, al_, P##0) \
    MFC(a31, ah_, P##2, cvec1) MF(a31, ah_, P##3) MF(a31, al_, P##2) \
    __builtin_amdgcn_s_setprio(0); }

// Merged dual-key top-2 insert: exact top-2 of {b1,b2,kA,kB}.
// b1' = min(b1,lo); b2' = min(min(max(b1,lo),hi),b2)  [v_min3-fusable].
#define INS2(sA, sB, slot) { \
    unsigned kA_ = (__float_as_uint(sA) & 0xFFFFFFC0u) | kn0; \
    unsigned kB_ = (__float_as_uint(sB) & 0xFFFFFFC0u) | kn1; \
    unsigned lo_ = kA_ < kB_ ? kA_ : kB_; \
    unsigned hi_ = kA_ < kB_ ? kB_ : kA_; \
    unsigned ob1_ = b1[slot]; \
    unsigned mx_ = ob1_ < lo_ ? lo_ : ob1_; \
    unsigned t2_ = mx_ < hi_ ? mx_ : hi_; \
    b1[slot] = ob1_ < lo_ ? ob1_ : lo_; \
    b2[slot] = t2_ < b2[slot] ? t2_ : b2[slot]; }

#define INSP(A0, A1, m) \
    INS2(A0[0], A1[0], (m) * 4 + 0) INS2(A0[1], A1[1], (m) * 4 + 1) \
    INS2(A0[2], A1[2], (m) * 4 + 2) INS2(A0[3], A1[3], (m) * 4 + 3)

    // Prime: load (kt=0, ds=0) into Ba; offB -> (0, ds1).
    PFB(Ba)
    offB += 1024;
    float cv0 = c2b[wbase + l15];
    float cv1 = c2b[wbase + 16 + l15];

#pragma unroll 1
    for (int kt = 0; kt < KW / 32; ++kt) {
        f32x4 cvec0 = (f32x4){cv0, cv0, cv0, cv0};
        f32x4 cvec1 = (f32x4){cv1, cv1, cv1, cv1};

        int ktn = (kt + 1) & 31;    // wraps at end; value then unused
        float cvn0 = c2b[wbase + ktn * 32 + l15];
        float cvn1 = c2b[wbase + ktn * 32 + 16 + l15];

        PFB(Bb) offB += 1024; STEP0(Ba)     // loads (kt,ds1); C-init from cvec
        PFB(Ba) offB += 1024; STEP(Bb, 1)   // loads (kt,ds2)
        PFB(Bb) offB += 1024; STEP(Ba, 2)   // loads (kt,ds3); offB -> (kt+1,ds0)
        if (kt != KW / 32 - 1) { PFB(Ba) }  // loads (kt+1,ds0)
        offB += 1024;                       // -> (kt+1,ds1)
        STEP(Bb, 3)

        const unsigned kn0 = (unsigned)(kt * 2);
        const unsigned kn1 = kn0 + 1u;
        INSP(a00, a01, 0) INSP(a10, a11, 1)
        INSP(a20, a21, 2) INSP(a30, a31, 3)

        cv0 = cvn0; cv1 = cvn1;
    }

    // Quad butterfly: merge two sorted-2 (key,idx) lists per step.
#pragma unroll
    for (int m = 0; m < 4; ++m)
#pragma unroll
        for (int r = 0; r < 4; ++r) {
            unsigned k1 = b1[m * 4 + r], k2 = b2[m * 4 + r];
            int i1 = ((wave * 64 + (int)(k1 & 63u)) << 4) | l15;
            int i2 = ((wave * 64 + (int)(k2 & 63u)) << 4) | l15;
#pragma unroll
            for (int msk = 1; msk < 16; msk <<= 1) {
                unsigned ok1 = (unsigned)__shfl_xor((int)k1, msk, 64);
                int      oi1 = __shfl_xor(i1, msk, 64);
                unsigned ok2 = (unsigned)__shfl_xor((int)k2, msk, 64);
                int      oi2 = __shfl_xor(i2, msk, 64);
                bool ow = ok1 < k1;
                unsigned w1k = ow ? ok1 : k1; int w1i = ow ? oi1 : i1;
                unsigned lsk = ow ? k1 : ok1; int lsi = ow ? i1 : oi1;
                unsigned wsk = ow ? ok2 : k2; int wsi = ow ? oi2 : i2;
                bool sw = lsk < wsk;
                k1 = w1k; i1 = w1i;
                k2 = sw ? lsk : wsk; i2 = sw ? lsi : wsi;
            }
            if (l15 == 0) {
                int p = m * 16 + quad * 4 + r;
                r1K[wave][p] = k1; r1I[wave][p] = i1;
                r2K[wave][p] = k2; r2I[wave][p] = i2;
            }
        }
    __syncthreads();

    // ---- cross-wave merge (t<64), results parked in LDS ----
    if (t < MB) {
        unsigned k1 = r1K[0][t], k2 = r2K[0][t];
        int      i1 = r1I[0][t], i2 = r2I[0][t];
#pragma unroll
        for (int w = 1; w < 4; ++w) {
            unsigned ok1 = r1K[w][t], ok2 = r2K[w][t];
            int      oi1 = r1I[w][t], oi2 = r2I[w][t];
            bool ow = ok1 < k1;
            unsigned w1k = ow ? ok1 : k1; int w1i = ow ? oi1 : i1;
            unsigned lsk = ow ? k1 : ok1; int lsi = ow ? i1 : oi1;
            unsigned wsk = ow ? ok2 : k2; int wsi = ow ? oi2 : i2;
            bool sw = lsk < wsk;
            k1 = w1k; i1 = w1i;
            k2 = sw ? lsk : wsk; i2 = sw ? lsi : wsi;
        }
        r1I[0][t] = i1;
        r2I[0][t] = i2;
    }
    __syncthreads();

    // ---- parallel fp64 rescore: 4 threads per point, 32 dims each ----
    {
        const int p   = t >> 2;
        const int sub = t & 3;
        const int i1 = r1I[0][p], i2 = r2I[0][p];
        const float* x  = latent + (size_t)(row0 + p) * D_DIM + sub * 32;
        const float* ca = coords + (size_t)i1 * D_DIM + sub * 32;
        const float* cb = coords + (size_t)i2 * D_DIM + sub * 32;
        double d1 = 0.0, d2 = 0.0;
#pragma unroll
        for (int q = 0; q < 8; ++q) {
            float4 xv = *(const float4*)(x + q * 4);
            float4 av = *(const float4*)(ca + q * 4);
            float4 bv = *(const float4*)(cb + q * 4);
            double e;
            e = (double)xv.x - (double)av.x; d1 += e * e;
            e = (double)xv.y - (double)av.y; d1 += e * e;
            e = (double)xv.z - (double)av.z; d1 += e * e;
            e = (double)xv.w - (double)av.w; d1 += e * e;
            e = (double)xv.x - (double)bv.x; d2 += e * e;
            e = (double)xv.y - (double)bv.y; d2 += e * e;
            e = (double)xv.z - (double)bv.z; d2 += e * e;
            e = (double)xv.w - (double)bv.w; d2 += e * e;
        }
        d1 += __shfl_xor(d1, 1, 64); d1 += __shfl_xor(d1, 2, 64);
        d2 += __shfl_xor(d2, 1, 64); d2 += __shfl_xor(d2, 2, 64);
        if (sub == 0) {
            bool second = (d2 < d1) || (d2 == d1 && i2 < i1);
            out[row0 + p] = second ? i2 : i1;
        }
    }
}

// ---------------------------------------------------------------------------
extern "C" void kernel_launch(void* const* d_in, const int* in_sizes, int n_in,
                              void* d_out, int out_size, void* d_ws, size_t ws_size,
                              hipStream_t stream) {
    const float* latent = (const float*)d_in[0];
    const float* coords = (const float*)d_in[1];
    int* out = (int*)d_out;

    // ws: chp [K*D] f16 | clp [K*D] f16 | c2b [K] f32
    f16*   chp = (f16*)d_ws;
    f16*   clp = chp + (size_t)K_CENT * D_DIM;
    float* c2b = (float*)(clp + (size_t)K_CENT * D_DIM);

    split_pack_c2<<<dim3(K_CENT * D_DIM / 1024), dim3(256), 0, stream>>>(coords, chp, clp, c2b);
    argmin_mfma<<<dim3(N_PTS / MB), dim3(256), 0, stream>>>(latent, coords, chp, clp, c2b, out);
}

// Round 11
// 232.445 us; speedup vs baseline: 1.0360x; 1.0360x over previous
//
#include <hip/hip_runtime.h>

// CentroidPool: N=65536 x K=4096 x D=128 fp32 -> argmin_k ||x - c_k|| (int32).
// Stage 1: f16x3-split MFMA GEMM (xh*ch + xh*cl + xl*ch, fp32 acc = c2 init),
//   top-2 via sortable packed keys, register ping-pong B pipeline, B pre-packed
//   in per-(tile,step,lane) fragment order -> every B load 64x16B coalesced.
// ROUND-24: revert r23's parallel epilogue (all-wave gather + 2 extra syncs
//   made argmin 183.5 vs r22's 178.8; waves 1-3 no longer retired early).
//   Back to r22's t<64 serial epilogue, with a GAP TEST: keys are monotone
//   bit-patterns of positive scores, so k2-k1 = score gap in ulps. Worst-case
//   split-path error ~100 ulp (dropped xl*cl ~1 ulp + fp32 MFMA accum) and
//   key quantization 2x64 ulp; gap > 2048 ulp (~20x margin) proves top-1 is
//   exact -> skip the fp64 rescore + its 22MB coords/latent re-gather for the
//   vast majority of points. Near-ties still rescored exactly in fp64.
//   split_pack_c2 stays in r23's vectorized float4 form.
// Output written directly by argmin blocks.

typedef _Float16 f16;
typedef f16  f16x4 __attribute__((ext_vector_type(4)));
typedef f16  f16x8 __attribute__((ext_vector_type(8)));
typedef float f32x4 __attribute__((ext_vector_type(4)));

constexpr int N_PTS  = 65536;
constexpr int K_CENT = 4096;
constexpr int D_DIM  = 128;
constexpr int MB     = 64;     // points per block (4 waves share them)
constexpr int KW     = 1024;   // centroids per wave (waves split K 4-ways)
constexpr float SOFF = 256.0f; // score offset => strictly positive scores
constexpr unsigned GAP_ULP = 2048u; // rescore-skip margin (see header note)

// ---------------------------------------------------------------------------
// Split coords to f16 h/l, pack into fragment order, compute c2+SOFF.
// Vectorized: one float4 (4 dims of one cent) per thread.
// dst = ((gt*4 + ds)*2 + n)*512 + lane*8 + j, j0 = d0&7 in {0,4} -> f16x4.
// c2: 32 threads per cent, pure shuffle reduce (masks 1..16 stay in-group).
// ---------------------------------------------------------------------------
__global__ __launch_bounds__(256) void split_pack_c2(const float* __restrict__ c,
                                                     f16* __restrict__ chp,
                                                     f16* __restrict__ clp,
                                                     float* __restrict__ c2b) {
    const int t = threadIdx.x;
    const int idx = blockIdx.x * 256 + t;      // float4 index over K*D/4
    const int cent = idx >> 5;                 // 32 float4 per cent
    const int d0 = (idx & 31) * 4;             // starting dim
    float4 v = *(const float4*)(c + (size_t)cent * D_DIM + d0);
    f16 h0 = (f16)v.x, h1 = (f16)v.y, h2 = (f16)v.z, h3 = (f16)v.w;
    f16 l0 = (f16)(v.x - (float)h0), l1 = (f16)(v.y - (float)h1);
    f16 l2 = (f16)(v.z - (float)h2), l3 = (f16)(v.w - (float)h3);
    int gt = cent >> 5, n = (cent >> 4) & 1, l15c = cent & 15;
    int ds = d0 >> 5, quad = (d0 >> 3) & 3, j0 = d0 & 7;
    int lane = quad * 16 + l15c;
    int dst = ((gt * 4 + ds) * 2 + n) * 512 + lane * 8 + j0;
    *(f16x4*)(chp + dst) = (f16x4){h0, h1, h2, h3};
    *(f16x4*)(clp + dst) = (f16x4){l0, l1, l2, l3};
    // c2 reduction across the cent's 32 threads.
    float s = v.x * v.x + v.y * v.y + v.z * v.z + v.w * v.w;
#pragma unroll
    for (int m = 1; m < 32; m <<= 1) s += __shfl_xor(s, m, 64);
    if ((t & 31) == 0) c2b[cent] = s + SOFF;
}

// ---------------------------------------------------------------------------
// Stage 1 + fused rescore. Block = 4 waves x 64 points; latent (-2x) split h/l
// in XOR-swizzled LDS. Wave w scans cents [w*1024,(w+1)*1024) in 32-wide
// k-tiles (2 n-groups). Ping-pong invariant: Ba = (kt, ds0), offB -> (kt,ds1).
// key = (bits(score)&~63)|kn, kn = kt*2+n (6b); cent = (wave*64+kn)*16 + l15.
// Epilogue: t<64 merges block top-2; gap>GAP_ULP proves top-1 -> write it,
// else exact fp64 rescore (tie -> smaller index).
// ---------------------------------------------------------------------------
__global__ __launch_bounds__(256, 2) void argmin_mfma(
        const float* __restrict__ latent,
        const float* __restrict__ coords,
        const f16*   __restrict__ chp,    // packed B hi
        const f16*   __restrict__ clp,    // packed B lo
        const float* __restrict__ c2b,
        int* __restrict__ out) {
    __shared__ f16 latH[MB * 128];
    __shared__ f16 latL[MB * 128];
    __shared__ unsigned r1K[4][MB]; __shared__ int r1I[4][MB];
    __shared__ unsigned r2K[4][MB]; __shared__ int r2I[4][MB];

    const int t    = threadIdx.x;
    const int wave = t >> 6;
    const int lane = t & 63;
    const int quad = lane >> 4;
    const int l15  = lane & 15;
    const int row0 = blockIdx.x * MB;

    {   // Stage latent: scale -2, split h/l, XOR-swizzle 16-B units.
        const float4* src = (const float4*)(latent + (size_t)row0 * D_DIM);
#pragma unroll
        for (int i = 0; i < 4; ++i) {
            int g  = i * 256 + t;          // float8 index in [0,1024)
            int r  = g >> 4;               // row (16 float8 per row)
            int c8 = g & 15;               // logical 16-B column
            float4 v0 = src[2 * g];
            float4 v1 = src[2 * g + 1];
            float xs[8] = {v0.x, v0.y, v0.z, v0.w, v1.x, v1.y, v1.z, v1.w};
            f16x8 hv, lv;
#pragma unroll
            for (int c = 0; c < 8; ++c) {
                float x = -2.0f * xs[c];
                f16 h = (f16)x;
                hv[c] = h;
                lv[c] = (f16)(x - (float)h);
            }
            int pc = ((c8 ^ (r & 15)) << 3);
            *(f16x8*)&latH[r * 128 + pc] = hv;
            *(f16x8*)&latL[r * 128 + pc] = lv;
        }
    }
    __syncthreads();

    unsigned b1[16], b2[16];
#pragma unroll
    for (int i = 0; i < 16; ++i) { b1[i] = 0xFFFFFFFFu; b2[i] = 0xFFFFFFFFu; }

    const int wbase = wave * KW;
    // Packed-B element offset of the next step's load: uniform +1024/step.
    unsigned offB = (unsigned)(wave * 32 * 4) * 1024u + (unsigned)(lane * 8);

    // Named ping-pong regs — never address-taken.
    f16x8 Ba0, Ba1, Ba2, Ba3, Bb0, Bb1, Bb2, Bb3;
    f32x4 a00, a01, a10, a11, a20, a21, a30, a31;

#define PFB(P) \
    P##0 = *(const f16x8*)(chp + offB); \
    P##1 = *(const f16x8*)(clp + offB); \
    P##2 = *(const f16x8*)(chp + offB + 512); \
    P##3 = *(const f16x8*)(clp + offB + 512);

#define MF(d, a, b) d = __builtin_amdgcn_mfma_f32_16x16x32_f16(a, b, d, 0, 0, 0);
#define MFC(d, a, b, c) d = __builtin_amdgcn_mfma_f32_16x16x32_f16(a, b, c, 0, 0, 0);

// ds>=1 step: accumulate into live accs. Prio 1 across the MFMA cluster.
#define STEP(P, ds) { \
    __builtin_amdgcn_s_setprio(1); \
    const int pc_ = ((((ds) << 2) + quad) ^ l15) << 3; \
    f16x8 ah_, al_; \
    ah_ = *(const f16x8*)&latH[(     l15) * 128 + pc_]; \
    al_ = *(const f16x8*)&latL[(     l15) * 128 + pc_]; \
    MF(a00, ah_, P##0) MF(a00, ah_, P##1) MF(a00, al_, P##0) \
    MF(a01, ah_, P##2) MF(a01, ah_, P##3) MF(a01, al_, P##2) \
    ah_ = *(const f16x8*)&latH[(16 + l15) * 128 + pc_]; \
    al_ = *(const f16x8*)&latL[(16 + l15) * 128 + pc_]; \
    MF(a10, ah_, P##0) MF(a10, ah_, P##1) MF(a10, al_, P##0) \
    MF(a11, ah_, P##2) MF(a11, ah_, P##3) MF(a11, al_, P##2) \
    ah_ = *(const f16x8*)&latH[(32 + l15) * 128 + pc_]; \
    al_ = *(const f16x8*)&latL[(32 + l15) * 128 + pc_]; \
    MF(a20, ah_, P##0) MF(a20, ah_, P##1) MF(a20, al_, P##0) \
    MF(a21, ah_, P##2) MF(a21, ah_, P##3) MF(a21, al_, P##2) \
    ah_ = *(const f16x8*)&latH[(48 + l15) * 128 + pc_]; \
    al_ = *(const f16x8*)&latL[(48 + l15) * 128 + pc_]; \
    MF(a30, ah_, P##0) MF(a30, ah_, P##1) MF(a30, al_, P##0) \
    MF(a31, ah_, P##2) MF(a31, ah_, P##3) MF(a31, al_, P##2) \
    __builtin_amdgcn_s_setprio(0); }

// ds==0 step: each acc's FIRST MFMA takes the c2 broadcast as C (no INIT pass).
#define STEP0(P) { \
    __builtin_amdgcn_s_setprio(1); \
    const int pc_ = (quad ^ l15) << 3; \
    f16x8 ah_, al_; \
    ah_ = *(const f16x8*)&latH[(     l15) * 128 + pc_]; \
    al_ = *(const f16x8*)&latL[(     l15) * 128 + pc_]; \
    MFC(a00, ah_, P##0, cvec0) MF(a00, ah_, P##1) MF(a00, al_, P##0) \
    MFC(a01, ah_, P##2, cvec1) MF(a01, ah_, P##3) MF(a01, al_, P##2) \
    ah_ = *(const f16x8*)&latH[(16 + l15) * 128 + pc_]; \
    al_ = *(const f16x8*)&latL[(16 + l15) * 128 + pc_]; \
    MFC(a10, ah_, P##0, cvec0) MF(a10, ah_, P##1) MF(a10, al_, P##0) \
    MFC(a11, ah_, P##2, cvec1) MF(a11, ah_, P##3) MF(a11, al_, P##2) \
    ah_ = *(const f16x8*)&latH[(32 + l15) * 128 + pc_]; \
    al_ = *(const f16x8*)&latL[(32 + l15) * 128 + pc_]; \
    MFC(a20, ah_, P##0, cvec0) MF(a20, ah_, P##1) MF(a20, al_, P##0) \
    MFC(a21, ah_, P##2, cvec1) MF(a21, ah_, P##3) MF(a21, al_, P##2) \
    ah_ = *(const f16x8*)&latH[(48 + l15) * 128 + pc_]; \
    al_ = *(const f16x8*)&latL[(48 + l15) * 128 + pc_]; \
    MFC(a30, ah_, P##0, cvec0) MF(a30, ah_, P##1) MF(a30, al_, P##0) \
    MFC(a31, ah_, P##2, cvec1) MF(a31, ah_, P##3) MF(a31, al_, P##2) \
    __builtin_amdgcn_s_setprio(0); }

// Merged dual-key top-2 insert: exact top-2 of {b1,b2,kA,kB}.
// b1' = min(b1,lo); b2' = min(min(max(b1,lo),hi),b2)  [v_min3-fusable].
#define INS2(sA, sB, slot) { \
    unsigned kA_ = (__float_as_uint(sA) & 0xFFFFFFC0u) | kn0; \
    unsigned kB_ = (__float_as_uint(sB) & 0xFFFFFFC0u) | kn1; \
    unsigned lo_ = kA_ < kB_ ? kA_ : kB_; \
    unsigned hi_ = kA_ < kB_ ? kB_ : kA_; \
    unsigned ob1_ = b1[slot]; \
    unsigned mx_ = ob1_ < lo_ ? lo_ : ob1_; \
    unsigned t2_ = mx_ < hi_ ? mx_ : hi_; \
    b1[slot] = ob1_ < lo_ ? ob1_ : lo_; \
    b2[slot] = t2_ < b2[slot] ? t2_ : b2[slot]; }

#define INSP(A0, A1, m) \
    INS2(A0[0], A1[0], (m) * 4 + 0) INS2(A0[1], A1[1], (m) * 4 + 1) \
    INS2(A0[2], A1[2], (m) * 4 + 2) INS2(A0[3], A1[3], (m) * 4 + 3)

    // Prime: load (kt=0, ds=0) into Ba; offB -> (0, ds1).
    PFB(Ba)
    offB += 1024;
    float cv0 = c2b[wbase + l15];
    float cv1 = c2b[wbase + 16 + l15];

#pragma unroll 1
    for (int kt = 0; kt < KW / 32; ++kt) {
        f32x4 cvec0 = (f32x4){cv0, cv0, cv0, cv0};
        f32x4 cvec1 = (f32x4){cv1, cv1, cv1, cv1};

        int ktn = (kt + 1) & 31;    // wraps at end; value then unused
        float cvn0 = c2b[wbase + ktn * 32 + l15];
        float cvn1 = c2b[wbase + ktn * 32 + 16 + l15];

        PFB(Bb) offB += 1024; STEP0(Ba)     // loads (kt,ds1); C-init from cvec
        PFB(Ba) offB += 1024; STEP(Bb, 1)   // loads (kt,ds2)
        PFB(Bb) offB += 1024; STEP(Ba, 2)   // loads (kt,ds3); offB -> (kt+1,ds0)
        if (kt != KW / 32 - 1) { PFB(Ba) }  // loads (kt+1,ds0)
        offB += 1024;                       // -> (kt+1,ds1)
        STEP(Bb, 3)

        const unsigned kn0 = (unsigned)(kt * 2);
        const unsigned kn1 = kn0 + 1u;
        INSP(a00, a01, 0) INSP(a10, a11, 1)
        INSP(a20, a21, 2) INSP(a30, a31, 3)

        cv0 = cvn0; cv1 = cvn1;
    }

    // Quad butterfly: merge two sorted-2 (key,idx) lists per step.
#pragma unroll
    for (int m = 0; m < 4; ++m)
#pragma unroll
        for (int r = 0; r < 4; ++r) {
            unsigned k1 = b1[m * 4 + r], k2 = b2[m * 4 + r];
            int i1 = ((wave * 64 + (int)(k1 & 63u)) << 4) | l15;
            int i2 = ((wave * 64 + (int)(k2 & 63u)) << 4) | l15;
#pragma unroll
            for (int msk = 1; msk < 16; msk <<= 1) {
                unsigned ok1 = (unsigned)__shfl_xor((int)k1, msk, 64);
                int      oi1 = __shfl_xor(i1, msk, 64);
                unsigned ok2 = (unsigned)__shfl_xor((int)k2, msk, 64);
                int      oi2 = __shfl_xor(i2, msk, 64);
                bool ow = ok1 < k1;
                unsigned w1k = ow ? ok1 : k1; int w1i = ow ? oi1 : i1;
                unsigned lsk = ow ? k1 : ok1; int lsi = ow ? i1 : oi1;
                unsigned wsk = ow ? ok2 : k2; int wsi = ow ? oi2 : i2;
                bool sw = lsk < wsk;
                k1 = w1k; i1 = w1i;
                k2 = sw ? lsk : wsk; i2 = sw ? lsi : wsi;
            }
            if (l15 == 0) {
                int p = m * 16 + quad * 4 + r;
                r1K[wave][p] = k1; r1I[wave][p] = i1;
                r2K[wave][p] = k2; r2I[wave][p] = i2;
            }
        }
    __syncthreads();

    // ---- fused epilogue: cross-wave merge + gap-gated exact fp64 rescore ----
    if (t < MB) {
        unsigned k1 = r1K[0][t], k2 = r2K[0][t];
        int      i1 = r1I[0][t], i2 = r2I[0][t];
#pragma unroll
        for (int w = 1; w < 4; ++w) {
            unsigned ok1 = r1K[w][t], ok2 = r2K[w][t];
            int      oi1 = r1I[w][t], oi2 = r2I[w][t];
            bool ow = ok1 < k1;
            unsigned w1k = ow ? ok1 : k1; int w1i = ow ? oi1 : i1;
            unsigned lsk = ow ? k1 : ok1; int lsi = ow ? i1 : oi1;
            unsigned wsk = ow ? ok2 : k2; int wsi = ow ? oi2 : i2;
            bool sw = lsk < wsk;
            k1 = w1k; i1 = w1i;
            k2 = sw ? lsk : wsk; i2 = sw ? lsi : wsi;
        }
        // Gap test: keys are monotone bit-patterns of positive fp32 scores;
        // (k2-k1) in ulps >> worst-case split error (~100 ulp + 128 ulp
        // quantization) proves i1 is the exact argmin.
        if (k2 - k1 > GAP_ULP) {
            out[row0 + t] = i1;
        } else {
            // Exact fp64 rescore of the two candidates. Tie -> smaller index.
            const float* x  = latent + (size_t)(row0 + t) * D_DIM;
            const float* ca = coords + (size_t)i1 * D_DIM;
            const float* cb = coords + (size_t)i2 * D_DIM;
            double d1 = 0.0, d2 = 0.0;
#pragma unroll
            for (int d = 0; d < D_DIM; d += 4) {
                float4 xv = *(const float4*)(x + d);
                float4 av = *(const float4*)(ca + d);
                float4 bv = *(const float4*)(cb + d);
                double e;
                e = (double)xv.x - (double)av.x; d1 += e * e;
                e = (double)xv.y - (double)av.y; d1 += e * e;
                e = (double)xv.z - (double)av.z; d1 += e * e;
                e = (double)xv.w - (double)av.w; d1 += e * e;
                e = (double)xv.x - (double)bv.x; d2 += e * e;
                e = (double)xv.y - (double)bv.y; d2 += e * e;
                e = (double)xv.z - (double)bv.z; d2 += e * e;
                e = (double)xv.w - (double)bv.w; d2 += e * e;
            }
            bool second = (d2 < d1) || (d2 == d1 && i2 < i1);
            out[row0 + t] = second ? i2 : i1;
        }
    }
}

// ---------------------------------------------------------------------------
extern "C" void kernel_launch(void* const* d_in, const int* in_sizes, int n_in,
                              void* d_out, int out_size, void* d_ws, size_t ws_size,
                              hipStream_t stream) {
    const float* latent = (const float*)d_in[0];
    const float* coords = (const float*)d_in[1];
    int* out = (int*)d_out;

    // ws: chp [K*D] f16 | clp [K*D] f16 | c2b [K] f32
    f16*   chp = (f16*)d_ws;
    f16*   clp = chp + (size_t)K_CENT * D_DIM;
    float* c2b = (float*)(clp + (size_t)K_CENT * D_DIM);

    split_pack_c2<<<dim3(K_CENT * D_DIM / 1024), dim3(256), 0, stream>>>(coords, chp, clp, c2b);
    argmin_mfma<<<dim3(N_PTS / MB), dim3(256), 0, stream>>>(latent, coords, chp, clp, c2b, out);
}

// Round 12
// 225.819 us; speedup vs baseline: 1.0664x; 1.0293x over previous
//
#include <hip/hip_runtime.h>

// CentroidPool: N=65536 x K=4096 x D=128 fp32 -> argmin_k ||x - c_k|| (int32).
// Stage 1: f16x3-split MFMA GEMM (xh*ch + xh*cl + xl*ch, fp32 acc = c2 init),
//   top-2 via sortable packed keys, register ping-pong B pipeline, B pre-packed
//   in per-(tile,step,lane) fragment order -> every B load 64x16B coalesced.
// ROUND-25: instruction diet on the r24 winner (232.4us, best).
//   (a) INS2 rewritten in canonical min3/med3 form: new-b1 = min(min(kA,kB),
//       ob1) [v_min3_u32 pattern], med = max(min(kA,kB), min(max(kA,kB), ob1))
//       [v_med3_u32 pattern], new-b2 = min(ob2, med). Algebraically identical
//       top-2 update; if the backend fuses, 8 -> 5 VALU/slot (-48 VALU/kt).
//   (b) Branchless loop: the last-kt PFB guard dropped -- the overrun read
//       lands in clp/c2b (allocated ws), values unused.
//   Occupancy note: HW VGPR tiers quantize at {64,128,256} (m69); this kernel
//   needs ~156 regs -> 2 waves/SIMD is a hard tier, 3 waves impossible. All
//   occupancy/scheduling levers closed by measurement (r14-r21).
// Output written directly by argmin blocks (fused gap-gated fp64 rescore).

typedef _Float16 f16;
typedef f16  f16x4 __attribute__((ext_vector_type(4)));
typedef f16  f16x8 __attribute__((ext_vector_type(8)));
typedef float f32x4 __attribute__((ext_vector_type(4)));

constexpr int N_PTS  = 65536;
constexpr int K_CENT = 4096;
constexpr int D_DIM  = 128;
constexpr int MB     = 64;     // points per block (4 waves share them)
constexpr int KW     = 1024;   // centroids per wave (waves split K 4-ways)
constexpr float SOFF = 256.0f; // score offset => strictly positive scores
constexpr unsigned GAP_ULP = 2048u; // rescore-skip margin (see r24 note)

// ---------------------------------------------------------------------------
// Split coords to f16 h/l, pack into fragment order, compute c2+SOFF.
// Vectorized: one float4 (4 dims of one cent) per thread.
// dst = ((gt*4 + ds)*2 + n)*512 + lane*8 + j, j0 = d0&7 in {0,4} -> f16x4.
// c2: 32 threads per cent, pure shuffle reduce (masks 1..16 stay in-group).
// ---------------------------------------------------------------------------
__global__ __launch_bounds__(256) void split_pack_c2(const float* __restrict__ c,
                                                     f16* __restrict__ chp,
                                                     f16* __restrict__ clp,
                                                     float* __restrict__ c2b) {
    const int t = threadIdx.x;
    const int idx = blockIdx.x * 256 + t;      // float4 index over K*D/4
    const int cent = idx >> 5;                 // 32 float4 per cent
    const int d0 = (idx & 31) * 4;             // starting dim
    float4 v = *(const float4*)(c + (size_t)cent * D_DIM + d0);
    f16 h0 = (f16)v.x, h1 = (f16)v.y, h2 = (f16)v.z, h3 = (f16)v.w;
    f16 l0 = (f16)(v.x - (float)h0), l1 = (f16)(v.y - (float)h1);
    f16 l2 = (f16)(v.z - (float)h2), l3 = (f16)(v.w - (float)h3);
    int gt = cent >> 5, n = (cent >> 4) & 1, l15c = cent & 15;
    int ds = d0 >> 5, quad = (d0 >> 3) & 3, j0 = d0 & 7;
    int lane = quad * 16 + l15c;
    int dst = ((gt * 4 + ds) * 2 + n) * 512 + lane * 8 + j0;
    *(f16x4*)(chp + dst) = (f16x4){h0, h1, h2, h3};
    *(f16x4*)(clp + dst) = (f16x4){l0, l1, l2, l3};
    // c2 reduction across the cent's 32 threads.
    float s = v.x * v.x + v.y * v.y + v.z * v.z + v.w * v.w;
#pragma unroll
    for (int m = 1; m < 32; m <<= 1) s += __shfl_xor(s, m, 64);
    if ((t & 31) == 0) c2b[cent] = s + SOFF;
}

// ---------------------------------------------------------------------------
// Stage 1 + fused rescore. Block = 4 waves x 64 points; latent (-2x) split h/l
// in XOR-swizzled LDS. Wave w scans cents [w*1024,(w+1)*1024) in 32-wide
// k-tiles (2 n-groups). Ping-pong invariant: Ba = (kt, ds0), offB -> (kt,ds1).
// key = (bits(score)&~63)|kn, kn = kt*2+n (6b); cent = (wave*64+kn)*16 + l15.
// Epilogue: t<64 merges block top-2; gap>GAP_ULP proves top-1 -> write it,
// else exact fp64 rescore (tie -> smaller index).
// ---------------------------------------------------------------------------
__global__ __launch_bounds__(256, 2) void argmin_mfma(
        const float* __restrict__ latent,
        const float* __restrict__ coords,
        const f16*   __restrict__ chp,    // packed B hi
        const f16*   __restrict__ clp,    // packed B lo
        const float* __restrict__ c2b,
        int* __restrict__ out) {
    __shared__ f16 latH[MB * 128];
    __shared__ f16 latL[MB * 128];
    __shared__ unsigned r1K[4][MB]; __shared__ int r1I[4][MB];
    __shared__ unsigned r2K[4][MB]; __shared__ int r2I[4][MB];

    const int t    = threadIdx.x;
    const int wave = t >> 6;
    const int lane = t & 63;
    const int quad = lane >> 4;
    const int l15  = lane & 15;
    const int row0 = blockIdx.x * MB;

    {   // Stage latent: scale -2, split h/l, XOR-swizzle 16-B units.
        const float4* src = (const float4*)(latent + (size_t)row0 * D_DIM);
#pragma unroll
        for (int i = 0; i < 4; ++i) {
            int g  = i * 256 + t;          // float8 index in [0,1024)
            int r  = g >> 4;               // row (16 float8 per row)
            int c8 = g & 15;               // logical 16-B column
            float4 v0 = src[2 * g];
            float4 v1 = src[2 * g + 1];
            float xs[8] = {v0.x, v0.y, v0.z, v0.w, v1.x, v1.y, v1.z, v1.w};
            f16x8 hv, lv;
#pragma unroll
            for (int c = 0; c < 8; ++c) {
                float x = -2.0f * xs[c];
                f16 h = (f16)x;
                hv[c] = h;
                lv[c] = (f16)(x - (float)h);
            }
            int pc = ((c8 ^ (r & 15)) << 3);
            *(f16x8*)&latH[r * 128 + pc] = hv;
            *(f16x8*)&latL[r * 128 + pc] = lv;
        }
    }
    __syncthreads();

    unsigned b1[16], b2[16];
#pragma unroll
    for (int i = 0; i < 16; ++i) { b1[i] = 0xFFFFFFFFu; b2[i] = 0xFFFFFFFFu; }

    const int wbase = wave * KW;
    // Packed-B element offset of the next step's load: uniform +1024/step.
    unsigned offB = (unsigned)(wave * 32 * 4) * 1024u + (unsigned)(lane * 8);

    // Named ping-pong regs — never address-taken.
    f16x8 Ba0, Ba1, Ba2, Ba3, Bb0, Bb1, Bb2, Bb3;
    f32x4 a00, a01, a10, a11, a20, a21, a30, a31;

#define PFB(P) \
    P##0 = *(const f16x8*)(chp + offB); \
    P##1 = *(const f16x8*)(clp + offB); \
    P##2 = *(const f16x8*)(chp + offB + 512); \
    P##3 = *(const f16x8*)(clp + offB + 512);

#define MF(d, a, b) d = __builtin_amdgcn_mfma_f32_16x16x32_f16(a, b, d, 0, 0, 0);
#define MFC(d, a, b, c) d = __builtin_amdgcn_mfma_f32_16x16x32_f16(a, b, c, 0, 0, 0);

// ds>=1 step: accumulate into live accs. Prio 1 across the MFMA cluster.
#define STEP(P, ds) { \
    __builtin_amdgcn_s_setprio(1); \
    const int pc_ = ((((ds) << 2) + quad) ^ l15) << 3; \
    f16x8 ah_, al_; \
    ah_ = *(const f16x8*)&latH[(     l15) * 128 + pc_]; \
    al_ = *(const f16x8*)&latL[(     l15) * 128 + pc_]; \
    MF(a00, ah_, P##0) MF(a00, ah_, P##1) MF(a00, al_, P##0) \
    MF(a01, ah_, P##2) MF(a01, ah_, P##3) MF(a01, al_, P##2) \
    ah_ = *(const f16x8*)&latH[(16 + l15) * 128 + pc_]; \
    al_ = *(const f16x8*)&latL[(16 + l15) * 128 + pc_]; \
    MF(a10, ah_, P##0) MF(a10, ah_, P##1) MF(a10, al_, P##0) \
    MF(a11, ah_, P##2) MF(a11, ah_, P##3) MF(a11, al_, P##2) \
    ah_ = *(const f16x8*)&latH[(32 + l15) * 128 + pc_]; \
    al_ = *(const f16x8*)&latL[(32 + l15) * 128 + pc_]; \
    MF(a20, ah_, P##0) MF(a20, ah_, P##1) MF(a20, al_, P##0) \
    MF(a21, ah_, P##2) MF(a21, ah_, P##3) MF(a21, al_, P##2) \
    ah_ = *(const f16x8*)&latH[(48 + l15) * 128 + pc_]; \
    al_ = *(const f16x8*)&latL[(48 + l15) * 128 + pc_]; \
    MF(a30, ah_, P##0) MF(a30, ah_, P##1) MF(a30, al_, P##0) \
    MF(a31, ah_, P##2) MF(a31, ah_, P##3) MF(a31, al_, P##2) \
    __builtin_amdgcn_s_setprio(0); }

// ds==0 step: each acc's FIRST MFMA takes the c2 broadcast as C (no INIT pass).
#define STEP0(P) { \
    __builtin_amdgcn_s_setprio(1); \
    const int pc_ = (quad ^ l15) << 3; \
    f16x8 ah_, al_; \
    ah_ = *(const f16x8*)&latH[(     l15) * 128 + pc_]; \
    al_ = *(const f16x8*)&latL[(     l15) * 128 + pc_]; \
    MFC(a00, ah_, P##0, cvec0) MF(a00, ah_, P##1) MF(a00, al_, P##0) \
    MFC(a01, ah_, P##2, cvec1) MF(a01, ah_, P##3) MF(a01, al_, P##2) \
    ah_ = *(const f16x8*)&latH[(16 + l15) * 128 + pc_]; \
    al_ = *(const f16x8*)&latL[(16 + l15) * 128 + pc_]; \
    MFC(a10, ah_, P##0, cvec0) MF(a10, ah_, P##1) MF(a10, al_, P##0) \
    MFC(a11, ah_, P##2, cvec1) MF(a11, ah_, P##3) MF(a11, al_, P##2) \
    ah_ = *(const f16x8*)&latH[(32 + l15) * 128 + pc_]; \
    al_ = *(const f16x8*)&latL[(32 + l15) * 128 + pc_]; \
    MFC(a20, ah_, P##0, cvec0) MF(a20, ah_, P##1) MF(a20, al_, P##0) \
    MFC(a21, ah_, P##2, cvec1) MF(a21, ah_, P##3) MF(a21, al_, P##2) \
    ah_ = *(const f16x8*)&latH[(48 + l15) * 128 + pc_]; \
    al_ = *(const f16x8*)&latL[(48 + l15) * 128 + pc_]; \
    MFC(a30, ah_, P##0, cvec0) MF(a30, ah_, P##1) MF(a30, al_, P##0) \
    MFC(a31, ah_, P##2, cvec1) MF(a31, ah_, P##3) MF(a31, al_, P##2) \
    __builtin_amdgcn_s_setprio(0); }

// Merged dual-key top-2 insert (exact top-2 of {b1,b2,kA,kB}), canonical
// min3/med3 form: nb1 = min(min(kA,kB), ob1)            [v_min3_u32]
//                 med = max(min(kA,kB), min(max(kA,kB), ob1))  [v_med3_u32]
//                 nb2 = min(ob2, med).
// med3(kA,kB,ob1) is the 2nd-smallest of the triple; 2nd of all four =
// min(ob2, that) since min of four = min(triple) <= ob1 <= ob2.
#define INS2(sA, sB, slot) { \
    unsigned kA_ = (__float_as_uint(sA) & 0xFFFFFFC0u) | kn0; \
    unsigned kB_ = (__float_as_uint(sB) & 0xFFFFFFC0u) | kn1; \
    unsigned ob1_ = b1[slot]; \
    unsigned lo_ = kA_ < kB_ ? kA_ : kB_; \
    unsigned hi_ = kA_ < kB_ ? kB_ : kA_; \
    unsigned m1_ = hi_ < ob1_ ? hi_ : ob1_; \
    unsigned med_ = lo_ > m1_ ? lo_ : m1_; \
    b1[slot] = lo_ < ob1_ ? lo_ : ob1_; \
    b2[slot] = med_ < b2[slot] ? med_ : b2[slot]; }

#define INSP(A0, A1, m) \
    INS2(A0[0], A1[0], (m) * 4 + 0) INS2(A0[1], A1[1], (m) * 4 + 1) \
    INS2(A0[2], A1[2], (m) * 4 + 2) INS2(A0[3], A1[3], (m) * 4 + 3)

    // Prime: load (kt=0, ds=0) into Ba; offB -> (0, ds1).
    PFB(Ba)
    offB += 1024;
    float cv0 = c2b[wbase + l15];
    float cv1 = c2b[wbase + 16 + l15];

#pragma unroll 1
    for (int kt = 0; kt < KW / 32; ++kt) {
        f32x4 cvec0 = (f32x4){cv0, cv0, cv0, cv0};
        f32x4 cvec1 = (f32x4){cv1, cv1, cv1, cv1};

        int ktn = (kt + 1) & 31;    // wraps at end; value then unused
        float cvn0 = c2b[wbase + ktn * 32 + l15];
        float cvn1 = c2b[wbase + ktn * 32 + 16 + l15];

        PFB(Bb) offB += 1024; STEP0(Ba)     // loads (kt,ds1); C-init from cvec
        PFB(Ba) offB += 1024; STEP(Bb, 1)   // loads (kt,ds2)
        PFB(Bb) offB += 1024; STEP(Ba, 2)   // loads (kt,ds3); offB -> (kt+1,ds0)
        PFB(Ba)                             // loads (kt+1,ds0); at kt=31 the
                                            // overrun lands in clp/c2b (alloc'd,
                                            // values unused) -> branchless loop
        offB += 1024;                       // -> (kt+1,ds1)
        STEP(Bb, 3)

        const unsigned kn0 = (unsigned)(kt * 2);
        const unsigned kn1 = kn0 + 1u;
        INSP(a00, a01, 0) INSP(a10, a11, 1)
        INSP(a20, a21, 2) INSP(a30, a31, 3)

        cv0 = cvn0; cv1 = cvn1;
    }

    // Quad butterfly: merge two sorted-2 (key,idx) lists per step.
#pragma unroll
    for (int m = 0; m < 4; ++m)
#pragma unroll
        for (int r = 0; r < 4; ++r) {
            unsigned k1 = b1[m * 4 + r], k2 = b2[m * 4 + r];
            int i1 = ((wave * 64 + (int)(k1 & 63u)) << 4) | l15;
            int i2 = ((wave * 64 + (int)(k2 & 63u)) << 4) | l15;
#pragma unroll
            for (int msk = 1; msk < 16; msk <<= 1) {
                unsigned ok1 = (unsigned)__shfl_xor((int)k1, msk, 64);
                int      oi1 = __shfl_xor(i1, msk, 64);
                unsigned ok2 = (unsigned)__shfl_xor((int)k2, msk, 64);
                int      oi2 = __shfl_xor(i2, msk, 64);
                bool ow = ok1 < k1;
                unsigned w1k = ow ? ok1 : k1; int w1i = ow ? oi1 : i1;
                unsigned lsk = ow ? k1 : ok1; int lsi = ow ? i1 : oi1;
                unsigned wsk = ow ? ok2 : k2; int wsi = ow ? oi2 : i2;
                bool sw = lsk < wsk;
                k1 = w1k; i1 = w1i;
                k2 = sw ? lsk : wsk; i2 = sw ? lsi : wsi;
            }
            if (l15 == 0) {
                int p = m * 16 + quad * 4 + r;
                r1K[wave][p] = k1; r1I[wave][p] = i1;
                r2K[wave][p] = k2; r2I[wave][p] = i2;
            }
        }
    __syncthreads();

    // ---- fused epilogue: cross-wave merge + gap-gated exact fp64 rescore ----
    if (t < MB) {
        unsigned k1 = r1K[0][t], k2 = r2K[0][t];
        int      i1 = r1I[0][t], i2 = r2I[0][t];
#pragma unroll
        for (int w = 1; w < 4; ++w) {
            unsigned ok1 = r1K[w][t], ok2 = r2K[w][t];
            int      oi1 = r1I[w][t], oi2 = r2I[w][t];
            bool ow = ok1 < k1;
            unsigned w1k = ow ? ok1 : k1; int w1i = ow ? oi1 : i1;
            unsigned lsk = ow ? k1 : ok1; int lsi = ow ? i1 : oi1;
            unsigned wsk = ow ? ok2 : k2; int wsi = ow ? oi2 : i2;
            bool sw = lsk < wsk;
            k1 = w1k; i1 = w1i;
            k2 = sw ? lsk : wsk; i2 = sw ? lsi : wsi;
        }
        // Gap test: keys are monotone bit-patterns of positive fp32 scores;
        // (k2-k1) in ulps >> worst-case split error (~100 ulp + 128 ulp
        // quantization) proves i1 is the exact argmin.
        if (k2 - k1 > GAP_ULP) {
            out[row0 + t] = i1;
        } else {
            // Exact fp64 rescore of the two candidates. Tie -> smaller index.
            const float* x  = latent + (size_t)(row0 + t) * D_DIM;
            const float* ca = coords + (size_t)i1 * D_DIM;
            const float* cb = coords + (size_t)i2 * D_DIM;
            double d1 = 0.0, d2 = 0.0;
#pragma unroll
            for (int d = 0; d < D_DIM; d += 4) {
                float4 xv = *(const float4*)(x + d);
                float4 av = *(const float4*)(ca + d);
                float4 bv = *(const float4*)(cb + d);
                double e;
                e = (double)xv.x - (double)av.x; d1 += e * e;
                e = (double)xv.y - (double)av.y; d1 += e * e;
                e = (double)xv.z - (double)av.z; d1 += e * e;
                e = (double)xv.w - (double)av.w; d1 += e * e;
                e = (double)xv.x - (double)bv.x; d2 += e * e;
                e = (double)xv.y - (double)bv.y; d2 += e * e;
                e = (double)xv.z - (double)bv.z; d2 += e * e;
                e = (double)xv.w - (double)bv.w; d2 += e * e;
            }
            bool second = (d2 < d1) || (d2 == d1 && i2 < i1);
            out[row0 + t] = second ? i2 : i1;
        }
    }
}

// ---------------------------------------------------------------------------
extern "C" void kernel_launch(void* const* d_in, const int* in_sizes, int n_in,
                              void* d_out, int out_size, void* d_ws, size_t ws_size,
                              hipStream_t stream) {
    const float* latent = (const float*)d_in[0];
    const float* coords = (const float*)d_in[1];
    int* out = (int*)d_out;

    // ws: chp [K*D] f16 | clp [K*D] f16 | c2b [K] f32
    f16*   chp = (f16*)d_ws;
    f16*   clp = chp + (size_t)K_CENT * D_DIM;
    float* c2b = (float*)(clp + (size_t)K_CENT * D_DIM);

    split_pack_c2<<<dim3(K_CENT * D_DIM / 1024), dim3(256), 0, stream>>>(coords, chp, clp, c2b);
    argmin_mfma<<<dim3(N_PTS / MB), dim3(256), 0, stream>>>(latent, coords, chp, clp, c2b, out);
}